// Round 1
// baseline (1038.942 us; speedup 1.0000x reference)
//
#include <hip/hip_runtime.h>
#include <cstdint>
#include <cstddef>

// Problem constants (fixed by setup_inputs)
#define N_B 32
#define L_P 4096
#define L_S 1024
#define D_MODEL 256
#define H_N 8
#define HD 32
#define GP 1024   // L_P/4 grouped protein length
#define GS 256    // L_S/4 grouped sm length

// ---------------------------------------------------------------------------
// Group-mean over 4 consecutive rows. Since L = 4*Lg, input row base
// n*L + 4*g == 4*(n*Lg + g) == 4*outrow, so we index purely by output row.
// One thread per output float4 (D/4 = 64 per row).
__global__ void group_mean_kernel(const float4* __restrict__ x,
                                  float4* __restrict__ xg, int total) {
    int gid = blockIdx.x * blockDim.x + threadIdx.x;
    if (gid >= total) return;
    int row = gid >> 6;          // output row
    int c   = gid & 63;          // float4 column
    const float4* p = x + (size_t)row * 256 + c;   // 4 input rows * 64 f4/row
    float4 a = p[0], b = p[64], cc = p[128], d = p[192];
    float4 r;
    r.x = 0.25f * (a.x + b.x + cc.x + d.x);
    r.y = 0.25f * (a.y + b.y + cc.y + d.y);
    r.z = 0.25f * (a.z + b.z + cc.z + d.z);
    r.w = 0.25f * (a.w + b.w + cc.w + d.w);
    xg[gid] = r;
}

// any() over groups of 4 mask ints
__global__ void group_mask_kernel(const int* __restrict__ m,
                                  int* __restrict__ mg, int total) {
    int gid = blockIdx.x * blockDim.x + threadIdx.x;
    if (gid >= total) return;
    const int* p = m + (size_t)gid * 4;
    mg[gid] = (p[0] | p[1] | p[2] | p[3]) ? 1 : 0;
}

// ---------------------------------------------------------------------------
// fp32 GEMM: C[M,256] = A[M,256] * W[256,256], written into head-major layout
// out[((n*H + h)*Gg + g)*32 + d]  where n=row>>lgG, g=row&(Gg-1), h=col>>5,
// d=col&31.  128x128 tile, 256 threads, 8x8 accumulators per thread, TK=16.
__global__ __launch_bounds__(256) void gemm_head_kernel(
        const float* __restrict__ A, const float* __restrict__ W,
        float* __restrict__ outp, int Gg, int lgG) {
    __shared__ float As[16][128];
    __shared__ float Bs[16][128];
    const int tid = threadIdx.x;
    const int tx = tid & 15;     // col group
    const int ty = tid >> 4;     // row group
    const int row0 = blockIdx.y * 128;
    const int col0 = blockIdx.x * 128;

    float acc[8][8];
#pragma unroll
    for (int i = 0; i < 8; i++)
#pragma unroll
        for (int j = 0; j < 8; j++) acc[i][j] = 0.f;

    for (int k0 = 0; k0 < D_MODEL; k0 += 16) {
        // A tile: 128 rows x 16 k -> transposed into As[k][row]
#pragma unroll
        for (int i = 0; i < 2; i++) {
            int r  = tid & 127;
            int kq = ((tid >> 7) << 1) + i;   // 0..3 (float4 group in k)
            float4 v = *(const float4*)&A[(size_t)(row0 + r) * 256 + k0 + kq * 4];
            As[kq * 4 + 0][r] = v.x;
            As[kq * 4 + 1][r] = v.y;
            As[kq * 4 + 2][r] = v.z;
            As[kq * 4 + 3][r] = v.w;
        }
        // W tile: 16 k x 128 cols, direct
#pragma unroll
        for (int i = 0; i < 2; i++) {
            int k = (tid >> 5) + i * 8;       // 0..15
            int c = (tid & 31) * 4;
            *(float4*)&Bs[k][c] =
                *(const float4*)&W[(size_t)(k0 + k) * 256 + col0 + c];
        }
        __syncthreads();
#pragma unroll
        for (int kk = 0; kk < 16; kk++) {
            float a[8], b[8];
            *(float4*)&a[0] = *(const float4*)&As[kk][ty * 8];
            *(float4*)&a[4] = *(const float4*)&As[kk][ty * 8 + 4];
            *(float4*)&b[0] = *(const float4*)&Bs[kk][tx * 8];
            *(float4*)&b[4] = *(const float4*)&Bs[kk][tx * 8 + 4];
#pragma unroll
            for (int i = 0; i < 8; i++)
#pragma unroll
                for (int j = 0; j < 8; j++) acc[i][j] += a[i] * b[j];
        }
        __syncthreads();
    }

    // write into head-major layout; cols tx*8..tx*8+7 stay inside one head
    int colb = col0 + tx * 8;
    int h = colb >> 5;
    int d = colb & 31;
#pragma unroll
    for (int i = 0; i < 8; i++) {
        int r = row0 + ty * 8 + i;
        int n = r >> lgG;
        int g = r & (Gg - 1);
        float* o = outp + (((size_t)n * H_N + h) * Gg + g) * HD + d;
        *(float4*)&o[0] = make_float4(acc[i][0], acc[i][1], acc[i][2], acc[i][3]);
        *(float4*)&o[4] = make_float4(acc[i][4], acc[i][5], acc[i][6], acc[i][7]);
    }
}

// ---------------------------------------------------------------------------
// Online-softmax attention stream: thread owns one query row; K/V tiles of
// 128 keys staged in LDS; scores in 16-key register chunks.
__device__ __forceinline__ void attn_stream(
        const float* __restrict__ Kbase, const float* __restrict__ Vbase,
        const int* __restrict__ maskcol, int Lk,
        const float* q, float* sK, float* sV, int* smk,
        float& m, float& lsum, float* acc, int tid) {
    for (int t0 = 0; t0 < Lk; t0 += 128) {
        __syncthreads();
        const float4* Ksrc = (const float4*)(Kbase + (size_t)t0 * HD);
        const float4* Vsrc = (const float4*)(Vbase + (size_t)t0 * HD);
        float4* dK = (float4*)sK;
        float4* dV = (float4*)sV;
#pragma unroll
        for (int i = 0; i < 4; i++) {
            dK[tid + i * 256] = Ksrc[tid + i * 256];
            dV[tid + i * 256] = Vsrc[tid + i * 256];
        }
        if (tid < 128) smk[tid] = maskcol[t0 + tid];
        __syncthreads();
#pragma unroll 1
        for (int c = 0; c < 128; c += 16) {
            float s[16];
#pragma unroll
            for (int j = 0; j < 16; j++) {
                const float* kr = sK + (size_t)(c + j) * HD;
                float dot = 0.f;
#pragma unroll
                for (int d = 0; d < HD; d++) dot += q[d] * kr[d];
                s[j] = smk[c + j] ? dot : dot - 1e6f;
            }
            float tmax = s[0];
#pragma unroll
            for (int j = 1; j < 16; j++) tmax = fmaxf(tmax, s[j]);
            float mnew = fmaxf(m, tmax);
            float sc = __expf(m - mnew);
            m = mnew;
            lsum *= sc;
#pragma unroll
            for (int d = 0; d < HD; d++) acc[d] *= sc;
#pragma unroll
            for (int j = 0; j < 16; j++) {
                float e = __expf(s[j] - mnew);
                lsum += e;
                const float* vr = sV + (size_t)(c + j) * HD;
#pragma unroll
                for (int d = 0; d < HD; d++) acc[d] += e * vr[d];
            }
        }
    }
}

__global__ __launch_bounds__(256) void attn_kernel(
        const float* __restrict__ Qd, const float* __restrict__ Kp,
        const float* __restrict__ Vp, const float* __restrict__ Ksd,
        const float* __restrict__ Vsd, const int* __restrict__ msm_g,
        const int* __restrict__ mprot_g, float* __restrict__ out) {
    __shared__ float sK[128 * HD];
    __shared__ float sV[128 * HD];
    __shared__ int smk[128];
    const int b = blockIdx.x;
    const int n = b >> 3;
    const int h = b & 7;
    const int tid = threadIdx.x;   // query index l (Gs == 256 == blockDim)

    float q[HD];
    const float4* qp =
        (const float4*)(Qd + (((size_t)n * H_N + h) * GS + tid) * HD);
#pragma unroll
    for (int i = 0; i < 8; i++) {
        float4 v = qp[i];
        q[i * 4 + 0] = v.x; q[i * 4 + 1] = v.y;
        q[i * 4 + 2] = v.z; q[i * 4 + 3] = v.w;
    }
    const int rowmask = msm_g[n * GS + tid];

    float m = -INFINITY, lsum = 0.f;
    float acc[HD];
#pragma unroll
    for (int d = 0; d < HD; d++) acc[d] = 0.f;

    // dp stream: keys = grouped protein (1024)
    attn_stream(Kp + ((size_t)n * H_N + h) * GP * HD,
                Vp + ((size_t)n * H_N + h) * GP * HD,
                mprot_g + (size_t)n * GP, GP, q, sK, sV, smk, m, lsum, acc, tid);
    float rdp[HD];
    {
        float inv = 1.f / lsum;
#pragma unroll
        for (int d = 0; d < HD; d++) rdp[d] = acc[d] * inv;
    }

    // dd stream: keys = grouped sm (256)
    m = -INFINITY; lsum = 0.f;
#pragma unroll
    for (int d = 0; d < HD; d++) acc[d] = 0.f;
    attn_stream(Ksd + ((size_t)n * H_N + h) * GS * HD,
                Vsd + ((size_t)n * H_N + h) * GS * HD,
                msm_g + (size_t)n * GS, GS, q, sK, sV, smk, m, lsum, acc, tid);

    float inv = 1.f / lsum;
    float4* op = (float4*)(out + ((size_t)n * GS + tid) * D_MODEL + h * HD);
#pragma unroll
    for (int i = 0; i < 8; i++) {
        float4 v;
        if (rowmask) {
            v.x = 0.5f * (rdp[i * 4 + 0] + acc[i * 4 + 0] * inv);
            v.y = 0.5f * (rdp[i * 4 + 1] + acc[i * 4 + 1] * inv);
            v.z = 0.5f * (rdp[i * 4 + 2] + acc[i * 4 + 2] * inv);
            v.w = 0.5f * (rdp[i * 4 + 3] + acc[i * 4 + 3] * inv);
        } else {
            v.x = v.y = v.z = v.w = 0.f;
        }
        op[i] = v;
    }
}

// ---------------------------------------------------------------------------
extern "C" void kernel_launch(void* const* d_in, const int* in_sizes, int n_in,
                              void* d_out, int out_size, void* d_ws,
                              size_t ws_size, hipStream_t stream) {
    const float* protein  = (const float*)d_in[0];
    const float* smx      = (const float*)d_in[1];
    const int*   mask_prot= (const int*)d_in[2];
    const int*   mask_sm  = (const int*)d_in[3];
    const float* Wk_p = (const float*)d_in[4];
    const float* Wv_p = (const float*)d_in[5];
    const float* Wq_d = (const float*)d_in[6];
    const float* Wk_d = (const float*)d_in[7];
    const float* Wv_d = (const float*)d_in[8];
    float* out = (float*)d_out;

    float* ws = (float*)d_ws;
    size_t off = 0;
    float* prot_g = ws + off; off += (size_t)N_B * GP * D_MODEL;   // 8.4M
    float* sm_g   = ws + off; off += (size_t)N_B * GS * D_MODEL;   // 2.1M
    float* Kp     = ws + off; off += (size_t)N_B * H_N * GP * HD;  // 8.4M
    float* Vp     = ws + off; off += (size_t)N_B * H_N * GP * HD;  // 8.4M
    float* Qd     = ws + off; off += (size_t)N_B * H_N * GS * HD;  // 2.1M
    float* Ksd    = ws + off; off += (size_t)N_B * H_N * GS * HD;  // 2.1M
    float* Vsd    = ws + off; off += (size_t)N_B * H_N * GS * HD;  // 2.1M
    int* mprot_g  = (int*)(ws + off); off += (size_t)N_B * GP;
    int* msm_g    = (int*)(ws + off); off += (size_t)N_B * GS;

    // 1. group means + masks
    {
        int totalP = N_B * GP * (D_MODEL / 4);
        group_mean_kernel<<<(totalP + 255) / 256, 256, 0, stream>>>(
            (const float4*)protein, (float4*)prot_g, totalP);
        int totalS = N_B * GS * (D_MODEL / 4);
        group_mean_kernel<<<(totalS + 255) / 256, 256, 0, stream>>>(
            (const float4*)smx, (float4*)sm_g, totalS);
        group_mask_kernel<<<(N_B * GP + 255) / 256, 256, 0, stream>>>(
            mask_prot, mprot_g, N_B * GP);
        group_mask_kernel<<<(N_B * GS + 255) / 256, 256, 0, stream>>>(
            mask_sm, msm_g, N_B * GS);
    }

    // 2. projections into head-major [N,H,G,32]
    gemm_head_kernel<<<dim3(2, (N_B * GP) / 128), 256, 0, stream>>>(
        prot_g, Wk_p, Kp, GP, 10);
    gemm_head_kernel<<<dim3(2, (N_B * GP) / 128), 256, 0, stream>>>(
        prot_g, Wv_p, Vp, GP, 10);
    gemm_head_kernel<<<dim3(2, (N_B * GS) / 128), 256, 0, stream>>>(
        sm_g, Wq_d, Qd, GS, 8);
    gemm_head_kernel<<<dim3(2, (N_B * GS) / 128), 256, 0, stream>>>(
        sm_g, Wk_d, Ksd, GS, 8);
    gemm_head_kernel<<<dim3(2, (N_B * GS) / 128), 256, 0, stream>>>(
        sm_g, Wv_d, Vsd, GS, 8);

    // 3. fused dual-stream masked attention + merge
    attn_kernel<<<N_B * H_N, 256, 0, stream>>>(Qd, Kp, Vp, Ksd, Vsd,
                                               msm_g, mprot_g, out);
}

// Round 2
// 375.851 us; speedup vs baseline: 2.7642x; 2.7642x over previous
//
#include <hip/hip_runtime.h>
#include <cstdint>
#include <cstddef>

// Problem constants (fixed by setup_inputs)
#define N_B 32
#define D_MODEL 256
#define H_N 8
#define HD 32
#define GP 1024   // grouped protein length
#define GS 256    // grouped sm length

typedef __attribute__((ext_vector_type(8))) short short8;   // 8 bf16 = 4 VGPRs
typedef __attribute__((ext_vector_type(4))) short short4v;  // 4 bf16 = 2 VGPRs
typedef __attribute__((ext_vector_type(4))) float floatx4;

__device__ __forceinline__ unsigned short f2bf(float f) {
    unsigned u = __float_as_uint(f);
    u = (u + 0x7FFFu + ((u >> 16) & 1u)) >> 16;   // RNE
    return (unsigned short)u;
}

// ---------------------------------------------------------------------------
// Group-mean over 4 consecutive rows, fp32 in -> bf16 out (row-major [M][256]).
// One thread per 4 output elements.
__global__ void group_mean_bf16(const float4* __restrict__ x,
                                ushort4* __restrict__ xg, int total) {
    int gid = blockIdx.x * blockDim.x + threadIdx.x;
    if (gid >= total) return;
    int row = gid >> 6;          // output row
    int c   = gid & 63;          // float4 column
    const float4* p = x + (size_t)row * 256 + c;   // 4 input rows * 64 f4/row
    float4 a = p[0], b = p[64], cc = p[128], d = p[192];
    ushort4 r;
    r.x = f2bf(0.25f * (a.x + b.x + cc.x + d.x));
    r.y = f2bf(0.25f * (a.y + b.y + cc.y + d.y));
    r.z = f2bf(0.25f * (a.z + b.z + cc.z + d.z));
    r.w = f2bf(0.25f * (a.w + b.w + cc.w + d.w));
    xg[gid] = r;
}

// any() over groups of 4 -> additive bias (0 if any set, -1e6 if all masked).
// Matches reference `logits - INF` exactly (softmax shift-invariance keeps the
// all-masked-row case identical).
__global__ void group_mask_bias(const int* __restrict__ m,
                                float* __restrict__ bias, int total) {
    int gid = blockIdx.x * blockDim.x + threadIdx.x;
    if (gid >= total) return;
    const int* p = m + (size_t)gid * 4;
    bias[gid] = (p[0] | p[1] | p[2] | p[3]) ? 0.0f : -1000000.0f;
}

// W [K=256][N=256] fp32 -> concatenated transposed bf16 WT [Ncat][256(k)]
__global__ void wtrans_bf16(const float* __restrict__ W0,
                            const float* __restrict__ W1,
                            const float* __restrict__ W2,
                            unsigned short* __restrict__ WT, int Ncat) {
    int t = blockIdx.x * blockDim.x + threadIdx.x;
    if (t >= Ncat * 256) return;
    int k = t & 255, np = t >> 8;            // WT[np][k]
    int p = np >> 8, col = np & 255;
    const float* W = (p == 0) ? W0 : (p == 1 ? W1 : W2);
    WT[t] = f2bf(W[(size_t)k * 256 + col]);
}

// ---------------------------------------------------------------------------
// bf16 MFMA GEMM: C[M,Ncat] = A[M,256] * W, outputs head-major bf16
// out[p][((n*8+h)*Gg+g)*32+d] with p = col>>8, h=(col>>5)&7, d=col&31.
// 128x128 tile, 4 waves, per-wave 4x4 grid of 16x16x32 MFMAs, BK=64.
// LDS stride 72 shorts (=9 x 16B): frag reads & staging writes spread
// uniformly over the 8 16B-segment classes -> conflict-free.
__global__ __launch_bounds__(256) void gemm_bf16(
        const unsigned short* __restrict__ A,
        const unsigned short* __restrict__ WT,
        unsigned short* __restrict__ o0, unsigned short* __restrict__ o1,
        unsigned short* __restrict__ o2, int Gg, int lgG) {
    __shared__ alignas(16) unsigned short As[128 * 72];
    __shared__ alignas(16) unsigned short Bs[128 * 72];
    const int tid = threadIdx.x;
    const int ln = tid & 63, wave = tid >> 6;
    const int m16 = ln & 15, quad = ln >> 4;
    const int wm = (wave & 1) * 64, wn = (wave >> 1) * 64;
    const int row0 = blockIdx.y * 128, col0 = blockIdx.x * 128;

    floatx4 acc[4][4] = {};

    const uint4* Ag = (const uint4*)A;
    const uint4* Bg = (const uint4*)WT;
    for (int k0 = 0; k0 < 256; k0 += 64) {
        __syncthreads();
#pragma unroll
        for (int i = 0; i < 4; i++) {
            int e = i * 256 + tid;          // 16B unit index, 0..1023
            int r = e >> 3, ks = e & 7;     // row, 16B-seg within 128B k-slice
            ((uint4*)As)[r * 9 + ks] = Ag[(size_t)(row0 + r) * 32 + (k0 >> 3) + ks];
            ((uint4*)Bs)[r * 9 + ks] = Bg[(size_t)(col0 + r) * 32 + (k0 >> 3) + ks];
        }
        __syncthreads();
#pragma unroll
        for (int kh = 0; kh < 2; kh++) {
            short8 af[4], bfr[4];
#pragma unroll
            for (int im = 0; im < 4; im++)
                af[im] = *(const short8*)&As[(wm + im * 16 + m16) * 72 + kh * 32 + quad * 8];
#pragma unroll
            for (int in = 0; in < 4; in++)
                bfr[in] = *(const short8*)&Bs[(wn + in * 16 + m16) * 72 + kh * 32 + quad * 8];
#pragma unroll
            for (int im = 0; im < 4; im++)
#pragma unroll
                for (int in = 0; in < 4; in++)
                    acc[im][in] = __builtin_amdgcn_mfma_f32_16x16x32_bf16(
                        af[im], bfr[in], acc[im][in], 0, 0, 0);
        }
    }
    // epilogue: C layout col=lane&15, row=quad*4+reg  [m89-verified]
#pragma unroll
    for (int im = 0; im < 4; im++) {
#pragma unroll
        for (int in = 0; in < 4; in++) {
            int colg = col0 + wn + in * 16 + m16;
            int p = colg >> 8, h = (colg >> 5) & 7, d = colg & 31;
            unsigned short* ob = (p == 0) ? o0 : (p == 1 ? o1 : o2);
#pragma unroll
            for (int r = 0; r < 4; r++) {
                int Mrow = row0 + wm + im * 16 + quad * 4 + r;
                int nb = Mrow >> lgG, g = Mrow & (Gg - 1);
                ob[(((size_t)nb * 8 + h) * Gg + g) * 32 + d] = f2bf(acc[im][in][r]);
            }
        }
    }
}

// ---------------------------------------------------------------------------
// Flash-MFMA attention. Wave owns 16 queries; 32-key chunks; per chunk:
// S = Q*K^T (2 MFMA), fp32 online softmax (16-lane shuffle reductions),
// P -> bf16 via padded LDS round-trip (C-layout -> A-layout), PV (2 MFMA).
__device__ __forceinline__ void attn_chunks(
        const uint4* __restrict__ Kg, const uint4* __restrict__ Vg,
        const float* __restrict__ bias, int nchunks, short8 qf,
        unsigned short* sK, unsigned short* sVT, unsigned short* sP,
        int tid, int m16, int quad,
        float* m, float* l, floatx4& o0, floatx4& o1) {
    for (int c = 0; c < nchunks; c++) {
        __syncthreads();                       // protect prev chunk's reads
        if (tid < 128) {                       // K: 32 keys x 32 d, global order
            ((uint4*)sK)[tid] = Kg[c * 128 + tid];
        } else {                               // V: transpose to sVT[d][key], stride 36
            int t2 = tid - 128;
            int key = t2 >> 2, dq = t2 & 3;
            union { uint4 u; unsigned short s[8]; } uu;
            uu.u = Vg[c * 128 + key * 4 + dq];
#pragma unroll
            for (int j = 0; j < 8; j++)
                sVT[(dq * 8 + j) * 36 + key] = uu.s[j];
        }
        __syncthreads();
        // S MFMAs: A=Q[q][d], B=K[d][key] (lane key=m16, k-span d=quad*8+j)
        short8 kf0 = *(const short8*)&sK[m16 * 32 + quad * 8];
        short8 kf1 = *(const short8*)&sK[(m16 + 16) * 32 + quad * 8];
        floatx4 z = {0.f, 0.f, 0.f, 0.f};
        floatx4 s0 = __builtin_amdgcn_mfma_f32_16x16x32_bf16(qf, kf0, z, 0, 0, 0);
        floatx4 s1 = __builtin_amdgcn_mfma_f32_16x16x32_bf16(qf, kf1, z, 0, 0, 0);
        float b0 = bias[c * 32 + m16];
        float b1 = bias[c * 32 + 16 + m16];
        float e0[4], e1[4];
#pragma unroll
        for (int r = 0; r < 4; r++) {          // row q = quad*4 + r
            float v0 = s0[r] + b0, v1 = s1[r] + b1;
            float mx = fmaxf(v0, v1);
#pragma unroll
            for (int off = 1; off < 16; off <<= 1)
                mx = fmaxf(mx, __shfl_xor(mx, off, 64));
            float mnew = fmaxf(m[r], mx);
            float sc = __expf(m[r] - mnew);
            e0[r] = __expf(v0 - mnew);
            e1[r] = __expf(v1 - mnew);
            float rs = e0[r] + e1[r];
#pragma unroll
            for (int off = 1; off < 16; off <<= 1)
                rs += __shfl_xor(rs, off, 64);
            l[r] = l[r] * sc + rs;
            m[r] = mnew;
            o0[r] *= sc;
            o1[r] *= sc;
        }
        // P: C-layout write (stride 40 -> 2-way max), A-layout read (b128)
#pragma unroll
        for (int r = 0; r < 4; r++) {
            sP[(quad * 4 + r) * 40 + m16] = f2bf(e0[r]);
            sP[(quad * 4 + r) * 40 + m16 + 16] = f2bf(e1[r]);
        }
        short8 pf = *(const short8*)&sP[m16 * 40 + quad * 8];
        union { short4v h[2]; short8 v; } va, vb;
        va.h[0] = *(const short4v*)&sVT[m16 * 36 + quad * 8];
        va.h[1] = *(const short4v*)&sVT[m16 * 36 + quad * 8 + 4];
        vb.h[0] = *(const short4v*)&sVT[(m16 + 16) * 36 + quad * 8];
        vb.h[1] = *(const short4v*)&sVT[(m16 + 16) * 36 + quad * 8 + 4];
        o0 = __builtin_amdgcn_mfma_f32_16x16x32_bf16(pf, va.v, o0, 0, 0, 0);
        o1 = __builtin_amdgcn_mfma_f32_16x16x32_bf16(pf, vb.v, o1, 0, 0, 0);
    }
}

__global__ __launch_bounds__(256) void attn_mfma(
        const unsigned short* __restrict__ Qd, const unsigned short* __restrict__ Kp,
        const unsigned short* __restrict__ Vp, const unsigned short* __restrict__ Ksd,
        const unsigned short* __restrict__ Vsd, const float* __restrict__ bias_p,
        const float* __restrict__ bias_s, float* __restrict__ out) {
    __shared__ alignas(16) unsigned short sK[32 * 32];
    __shared__ alignas(16) unsigned short sVT[32 * 36];
    __shared__ alignas(16) unsigned short sP[4][16 * 40];
    const int b = blockIdx.x;
    const int n = b >> 5, h = (b >> 2) & 7, qq = b & 3;
    const int tid = threadIdx.x, wave = tid >> 6, ln = tid & 63;
    const int m16 = ln & 15, quad = ln >> 4;
    const int q0 = qq * 64 + wave * 16;

    // Q A-fragment: lane holds Q[q0+m16][quad*8 .. +7]
    short8 qf = *(const short8*)&Qd[(((size_t)n * 8 + h) * GS + q0 + m16) * 32 + quad * 8];

    float m_dp[4] = {-1e30f, -1e30f, -1e30f, -1e30f}, l_dp[4] = {0, 0, 0, 0};
    floatx4 odp0 = {}, odp1 = {};
    attn_chunks((const uint4*)Kp + ((size_t)n * 8 + h) * GP * 4,
                (const uint4*)Vp + ((size_t)n * 8 + h) * GP * 4,
                bias_p + (size_t)n * GP, GP / 32, qf, sK, sVT, sP[wave],
                tid, m16, quad, m_dp, l_dp, odp0, odp1);

    float m_dd[4] = {-1e30f, -1e30f, -1e30f, -1e30f}, l_dd[4] = {0, 0, 0, 0};
    floatx4 odd0 = {}, odd1 = {};
    attn_chunks((const uint4*)Ksd + ((size_t)n * 8 + h) * GS * 4,
                (const uint4*)Vsd + ((size_t)n * 8 + h) * GS * 4,
                bias_s + (size_t)n * GS, GS / 32, qf, sK, sVT, sP[wave],
                tid, m16, quad, m_dd, l_dd, odd0, odd1);

#pragma unroll
    for (int r = 0; r < 4; r++) {
        int qrow = q0 + quad * 4 + r;
        bool rm = (bias_s[(size_t)n * GS + qrow] == 0.0f);   // row unmasked?
        float idp = 1.f / l_dp[r], idd = 1.f / l_dd[r];
        float v0 = rm ? 0.5f * (odp0[r] * idp + odd0[r] * idd) : 0.f;
        float v1 = rm ? 0.5f * (odp1[r] * idp + odd1[r] * idd) : 0.f;
        float* ob = out + ((size_t)n * GS + qrow) * 256 + h * 32;
        ob[m16] = v0;
        ob[16 + m16] = v1;
    }
}

// ---------------------------------------------------------------------------
extern "C" void kernel_launch(void* const* d_in, const int* in_sizes, int n_in,
                              void* d_out, int out_size, void* d_ws,
                              size_t ws_size, hipStream_t stream) {
    const float* protein   = (const float*)d_in[0];
    const float* smx       = (const float*)d_in[1];
    const int*   mask_prot = (const int*)d_in[2];
    const int*   mask_sm   = (const int*)d_in[3];
    const float* Wk_p = (const float*)d_in[4];
    const float* Wv_p = (const float*)d_in[5];
    const float* Wq_d = (const float*)d_in[6];
    const float* Wk_d = (const float*)d_in[7];
    const float* Wv_d = (const float*)d_in[8];
    float* out = (float*)d_out;

    char* ws = (char*)d_ws;
    unsigned short* prot_g = (unsigned short*)ws; ws += (size_t)N_B * GP * 256 * 2;
    unsigned short* sm_g   = (unsigned short*)ws; ws += (size_t)N_B * GS * 256 * 2;
    unsigned short* WTbig  = (unsigned short*)ws; ws += (size_t)512 * 256 * 2;
    unsigned short* WTsml  = (unsigned short*)ws; ws += (size_t)768 * 256 * 2;
    unsigned short* Kp     = (unsigned short*)ws; ws += (size_t)N_B * H_N * GP * 32 * 2;
    unsigned short* Vp     = (unsigned short*)ws; ws += (size_t)N_B * H_N * GP * 32 * 2;
    unsigned short* Qd     = (unsigned short*)ws; ws += (size_t)N_B * H_N * GS * 32 * 2;
    unsigned short* Ksd    = (unsigned short*)ws; ws += (size_t)N_B * H_N * GS * 32 * 2;
    unsigned short* Vsd    = (unsigned short*)ws; ws += (size_t)N_B * H_N * GS * 32 * 2;
    float* bias_p = (float*)ws; ws += (size_t)N_B * GP * 4;
    float* bias_s = (float*)ws; ws += (size_t)N_B * GS * 4;

    // 1. grouping (fp32 -> bf16) + mask biases
    {
        int totalP = N_B * GP * 64;
        group_mean_bf16<<<totalP / 256, 256, 0, stream>>>(
            (const float4*)protein, (ushort4*)prot_g, totalP);
        int totalS = N_B * GS * 64;
        group_mean_bf16<<<totalS / 256, 256, 0, stream>>>(
            (const float4*)smx, (ushort4*)sm_g, totalS);
        group_mask_bias<<<(N_B * GP) / 256, 256, 0, stream>>>(
            mask_prot, bias_p, N_B * GP);
        group_mask_bias<<<(N_B * GS) / 256, 256, 0, stream>>>(
            mask_sm, bias_s, N_B * GS);
    }

    // 2. weight transpose + concat (bf16, k-contiguous rows for B-frags)
    wtrans_bf16<<<(512 * 256) / 256, 256, 0, stream>>>(Wk_p, Wv_p, Wv_p, WTbig, 512);
    wtrans_bf16<<<(768 * 256) / 256, 256, 0, stream>>>(Wq_d, Wk_d, Wv_d, WTsml, 768);

    // 3. MFMA projections -> head-major bf16
    gemm_bf16<<<dim3(4, (N_B * GP) / 128), 256, 0, stream>>>(
        prot_g, WTbig, Kp, Vp, Vp, GP, 10);
    gemm_bf16<<<dim3(6, (N_B * GS) / 128), 256, 0, stream>>>(
        sm_g, WTsml, Qd, Ksd, Vsd, GS, 8);

    // 4. fused dual-stream flash-MFMA attention + merge
    attn_mfma<<<N_B * H_N * 4, 256, 0, stream>>>(Qd, Kp, Vp, Ksd, Vsd,
                                                 bias_p, bias_s, out);
}

// Round 4
// 329.938 us; speedup vs baseline: 3.1489x; 1.1392x over previous
//
#include <hip/hip_runtime.h>
#include <cstdint>
#include <cstddef>

// Problem constants (fixed by setup_inputs)
#define N_B 32
#define D_MODEL 256
#define H_N 8
#define HD 32
#define GP 1024   // grouped protein length
#define GS 256    // grouped sm length
#define LOG2E 1.4426950408889634f

typedef __attribute__((ext_vector_type(8))) short short8;   // 8 bf16 = 4 VGPRs
typedef __attribute__((ext_vector_type(4))) float floatx4;

#if __has_builtin(__builtin_amdgcn_exp2f)
#define EXP2(x) __builtin_amdgcn_exp2f(x)
#else
#define EXP2(x) exp2f(x)
#endif

__device__ __forceinline__ unsigned short f2bf(float f) {
    unsigned u = __float_as_uint(f);
    u = (u + 0x7FFFu + ((u >> 16) & 1u)) >> 16;   // RNE
    return (unsigned short)u;
}

// pack two floats -> bf16x2 (lo = a, hi = b), round-half-up via +0x8000
__device__ __forceinline__ unsigned pack_bf16(float a, float b) {
    unsigned ua = __float_as_uint(a) + 0x8000u;
    unsigned ub = __float_as_uint(b) + 0x8000u;
    return __builtin_amdgcn_perm(ub, ua, 0x07060302);  // [b.hi16][a.hi16]
}

// ---------------------------------------------------------------------------
// Group-mean over 4 consecutive rows, fp32 in -> bf16 out (row-major [M][256]).
__global__ void group_mean_bf16(const float4* __restrict__ x,
                                ushort4* __restrict__ xg, int total) {
    int gid = blockIdx.x * blockDim.x + threadIdx.x;
    if (gid >= total) return;
    int row = gid >> 6;
    int c   = gid & 63;
    const float4* p = x + (size_t)row * 256 + c;
    float4 a = p[0], b = p[64], cc = p[128], d = p[192];
    ushort4 r;
    r.x = f2bf(0.25f * (a.x + b.x + cc.x + d.x));
    r.y = f2bf(0.25f * (a.y + b.y + cc.y + d.y));
    r.z = f2bf(0.25f * (a.z + b.z + cc.z + d.z));
    r.w = f2bf(0.25f * (a.w + b.w + cc.w + d.w));
    xg[gid] = r;
}

// any() over groups of 4 -> additive bias in log2 domain (0 or -1e6*log2e).
__global__ void group_mask_bias(const int* __restrict__ m,
                                float* __restrict__ bias, int total) {
    int gid = blockIdx.x * blockDim.x + threadIdx.x;
    if (gid >= total) return;
    const int* p = m + (size_t)gid * 4;
    bias[gid] = (p[0] | p[1] | p[2] | p[3]) ? 0.0f : -1442695.0f;
}

// ---------------------------------------------------------------------------
// W [K=256][N=256] fp32 -> concatenated transposed bf16 WT[p*256+col][k].
// 64x64 tiles via LDS: coalesced reads AND writes.
// R4 fix: drain loop now covers the full 64-short k-tile (2048 dwords),
// was j<2 / kq&7 writing only k<16 (left 3/4 of WT poisoned).
__global__ __launch_bounds__(256) void wtrans_bf16(
        const float* __restrict__ W0, const float* __restrict__ W1,
        const float* __restrict__ W2, unsigned short* __restrict__ WT) {
    __shared__ unsigned short sT[64 * 65];
    int p = blockIdx.y;
    int kt = blockIdx.x >> 2, ct = blockIdx.x & 3;
    const float* W = (p == 0) ? W0 : (p == 1 ? W1 : W2);
    int k0 = kt * 64, c0 = ct * 64;
    int t = threadIdx.x;
#pragma unroll
    for (int j = 0; j < 4; j++) {
        int idx = j * 256 + t;
        int kr = idx >> 4, cf = idx & 15;
        float4 v = *(const float4*)&W[(size_t)(k0 + kr) * 256 + c0 + cf * 4];
        sT[(cf * 4 + 0) * 65 + kr] = f2bf(v.x);
        sT[(cf * 4 + 1) * 65 + kr] = f2bf(v.y);
        sT[(cf * 4 + 2) * 65 + kr] = f2bf(v.z);
        sT[(cf * 4 + 3) * 65 + kr] = f2bf(v.w);
    }
    __syncthreads();
#pragma unroll
    for (int j = 0; j < 8; j++) {
        int idx = j * 256 + t;
        int cw = idx >> 5, kq = idx & 31;
        unsigned lo = sT[cw * 65 + kq * 2];
        unsigned hi = sT[cw * 65 + kq * 2 + 1];
        ((unsigned*)WT)[((size_t)p * 256 + c0 + cw) * 128 + (k0 >> 1) + kq] =
            lo | (hi << 16);
    }
}

// ---------------------------------------------------------------------------
// Transpose head-major V [nh][Gk][32] -> Vt [nh][32][Gk], with per-32-key
// column permutation pos = 2*(k&15) + (k>>4) so attention's packed P-pair
// writes (keys m16, m16+16 adjacent) match the MFMA k-order.
__global__ __launch_bounds__(256) void vtrans(
        const unsigned short* __restrict__ V, unsigned short* __restrict__ Vt,
        int Gk) {
    __shared__ unsigned short sT[32 * 132];
    int nh = blockIdx.y, kbase = blockIdx.x << 7;   // 128-key slab
    const uint4* src = (const uint4*)(V + ((size_t)nh * Gk + kbase) * 32);
    int t = threadIdx.x;
#pragma unroll
    for (int j = 0; j < 2; j++) {
        int idx = j * 256 + t;
        int kk = idx >> 2, dq = idx & 3;
        union { uint4 u; unsigned short s[8]; } w;
        w.u = src[kk * 4 + dq];
#pragma unroll
        for (int e = 0; e < 8; e++)
            sT[(dq * 8 + e) * 132 + kk] = w.s[e];
    }
    __syncthreads();
#pragma unroll
    for (int j = 0; j < 2; j++) {
        int idx = j * 256 + t;
        int d = idx >> 4, pu = idx & 15;
        union { uint4 u; unsigned short s[8]; } w;
#pragma unroll
        for (int e = 0; e < 8; e++) {
            int p = pu * 8 + e;
            int chunk = p >> 5, p32 = p & 31;
            int k32 = (p32 >> 1) + ((p32 & 1) << 4);
            w.s[e] = sT[d * 132 + chunk * 32 + k32];
        }
        *(uint4*)(Vt + ((size_t)nh * 32 + d) * Gk + kbase + pu * 8) = w.u;
    }
}

// ---------------------------------------------------------------------------
// bf16 MFMA GEMM with global_load_lds(16B) staging into a seg-rotated
// unpadded LDS layout: unit (row, s) holds global 16B-seg (s - row)&7.
// Frag read for global seg sg at row r is at s = (sg + r)&7 -> conflict-free
// b128 reads AND lane-linear LDS dest for the async copy.
__global__ __launch_bounds__(256) void gemm_bf16(
        const unsigned short* __restrict__ A,
        const unsigned short* __restrict__ WT,
        unsigned short* __restrict__ o0, unsigned short* __restrict__ o1,
        unsigned short* __restrict__ o2, int Gg, int lgG, float scale0) {
    __shared__ alignas(16) unsigned short As[128 * 64];
    __shared__ alignas(16) unsigned short Bs[128 * 64];
    const int tid = threadIdx.x;
    const int ln = tid & 63, wave = tid >> 6;
    const int m16 = ln & 15, quad = ln >> 4;
    const int wm = (wave & 1) * 64, wn = (wave >> 1) * 64;
    const int row0 = blockIdx.y * 128, col0 = blockIdx.x * 128;

    // staging lane constants: slab j covers units (j*4+wave)*64 + ln
    const uint4* gA[4];
    const uint4* gB[4];
    unsigned ldsoff[4];
#pragma unroll
    for (int j = 0; j < 4; j++) {
        int u = (j * 4 + wave) * 64 + ln;
        int r = u >> 3, s = u & 7;
        int sg = (s - r) & 7;
        gA[j] = (const uint4*)A + (size_t)(row0 + r) * 32 + sg;
        gB[j] = (const uint4*)WT + (size_t)(col0 + r) * 32 + sg;
        ldsoff[j] = (unsigned)((j * 4 + wave) * 512);   // shorts
    }
    // frag read byte-addresses (k0-invariant; kh toggles bit 6)
    int aaddr[4], baddr[4];
#pragma unroll
    for (int i = 0; i < 4; i++) {
        int rA = wm + i * 16 + m16;
        aaddr[i] = rA * 128 + ((quad + rA) & 7) * 16;
        int rB = wn + i * 16 + m16;
        baddr[i] = rB * 128 + ((quad + rB) & 7) * 16;
    }

    floatx4 acc[4][4] = {};
    for (int ko = 0; ko < 32; ko += 8) {     // k in uint4 units (256/8)
        __syncthreads();
#pragma unroll
        for (int j = 0; j < 4; j++) {
            __builtin_amdgcn_global_load_lds(
                (const __attribute__((address_space(1))) void*)(gA[j] + ko),
                (__attribute__((address_space(3))) void*)&As[ldsoff[j]], 16, 0, 0);
            __builtin_amdgcn_global_load_lds(
                (const __attribute__((address_space(1))) void*)(gB[j] + ko),
                (__attribute__((address_space(3))) void*)&Bs[ldsoff[j]], 16, 0, 0);
        }
        __syncthreads();
#pragma unroll
        for (int kh = 0; kh < 2; kh++) {
            short8 af[4], bfr[4];
#pragma unroll
            for (int i = 0; i < 4; i++) {
                af[i]  = *(const short8*)((const char*)As + (aaddr[i] ^ (kh << 6)));
                bfr[i] = *(const short8*)((const char*)Bs + (baddr[i] ^ (kh << 6)));
            }
#pragma unroll
            for (int im = 0; im < 4; im++)
#pragma unroll
                for (int in = 0; in < 4; in++)
                    acc[im][in] = __builtin_amdgcn_mfma_f32_16x16x32_bf16(
                        af[im], bfr[in], acc[im][in], 0, 0, 0);
        }
    }
    // epilogue: C layout col=lane&15, row=quad*4+reg; head-major bf16 out
#pragma unroll
    for (int im = 0; im < 4; im++) {
#pragma unroll
        for (int in = 0; in < 4; in++) {
            int colg = col0 + wn + in * 16 + m16;
            int p = colg >> 8, h = (colg >> 5) & 7, d = colg & 31;
            unsigned short* ob = (p == 0) ? o0 : (p == 1 ? o1 : o2);
            float sc = (p == 0) ? scale0 : 1.0f;
#pragma unroll
            for (int r = 0; r < 4; r++) {
                int Mrow = row0 + wm + im * 16 + quad * 4 + r;
                int nb = Mrow >> lgG, g = Mrow & (Gg - 1);
                ob[(((size_t)nb * 8 + h) * Gg + g) * 32 + d] = f2bf(acc[im][in][r] * sc);
            }
        }
    }
}

// ---------------------------------------------------------------------------
// Barrier-free flash attention: K B-frags and V^T A-frags straight from
// global; no running max (scores bounded, mask bias underflows to 0);
// per-lane partial l, reduced once at the end. P round-trips a per-wave
// LDS tile (packed b32 writes, aligned b128 reads, stride 20 dwords).
__device__ __forceinline__ void attn_stream(
        const unsigned short* __restrict__ Kb,
        const unsigned short* __restrict__ Vtb,
        const float* __restrict__ bias, int Lk, short8 qf, unsigned* sPw,
        int m16, int quad, float* l, floatx4& o0, floatx4& o1) {
    const uint4* K4 = (const uint4*)Kb;
    const uint4* V4 = (const uint4*)Vtb;
    const int Gk8 = Lk >> 3;
    const int nchunks = Lk >> 5;
    for (int c = 0; c < nchunks; c++) {
        union { uint4 u; short8 v; } kf0, kf1, vf0, vf1, pf;
        kf0.u = K4[(c * 32 + m16) * 4 + quad];
        kf1.u = K4[(c * 32 + 16 + m16) * 4 + quad];
        vf0.u = V4[(size_t)m16 * Gk8 + c * 4 + quad];
        vf1.u = V4[(size_t)(16 + m16) * Gk8 + c * 4 + quad];
        floatx4 z = {0.f, 0.f, 0.f, 0.f};
        floatx4 s0 = __builtin_amdgcn_mfma_f32_16x16x32_bf16(qf, kf0.v, z, 0, 0, 0);
        floatx4 s1 = __builtin_amdgcn_mfma_f32_16x16x32_bf16(qf, kf1.v, z, 0, 0, 0);
        float b0 = bias[c * 32 + m16];
        float b1 = bias[c * 32 + 16 + m16];
#pragma unroll
        for (int r = 0; r < 4; r++) {            // row q = quad*4 + r
            float e0 = EXP2(s0[r] + b0);
            float e1 = EXP2(s1[r] + b1);
            l[r] += e0 + e1;
            sPw[(quad * 4 + r) * 20 + m16] = pack_bf16(e0, e1);
        }
        pf.u = *(const uint4*)&sPw[m16 * 20 + quad * 4];
        o0 = __builtin_amdgcn_mfma_f32_16x16x32_bf16(pf.v, vf0.v, o0, 0, 0, 0);
        o1 = __builtin_amdgcn_mfma_f32_16x16x32_bf16(pf.v, vf1.v, o1, 0, 0, 0);
    }
}

__global__ __launch_bounds__(256) void attn_mfma(
        const unsigned short* __restrict__ Qd, const unsigned short* __restrict__ Kp,
        const unsigned short* __restrict__ Vpt, const unsigned short* __restrict__ Ksd,
        const unsigned short* __restrict__ Vsdt, const float* __restrict__ bias_p,
        const float* __restrict__ bias_s, float* __restrict__ out) {
    __shared__ alignas(16) unsigned sP[4][16 * 20];
    const int b = blockIdx.x;
    const int n = b >> 5, h = (b >> 2) & 7, qq = b & 3;
    const int tid = threadIdx.x, wave = tid >> 6, ln = tid & 63;
    const int m16 = ln & 15, quad = ln >> 4;
    const int q0 = qq * 64 + wave * 16;
    unsigned* sPw = sP[wave];

    union { uint4 u; short8 v; } qf;
    qf.u = ((const uint4*)Qd)[(((size_t)n * 8 + h) * GS + q0 + m16) * 4 + quad];

    float l_dp[4] = {0, 0, 0, 0}, l_dd[4] = {0, 0, 0, 0};
    floatx4 odp0 = {}, odp1 = {}, odd0 = {}, odd1 = {};

    attn_stream(Kp + ((size_t)n * 8 + h) * GP * 32,
                Vpt + ((size_t)n * 8 + h) * GP * 32,
                bias_p + (size_t)n * GP, GP, qf.v, sPw, m16, quad,
                l_dp, odp0, odp1);
    attn_stream(Ksd + ((size_t)n * 8 + h) * GS * 32,
                Vsdt + ((size_t)n * 8 + h) * GS * 32,
                bias_s + (size_t)n * GS, GS, qf.v, sPw, m16, quad,
                l_dd, odd0, odd1);

#pragma unroll
    for (int r = 0; r < 4; r++) {
#pragma unroll
        for (int off = 1; off < 16; off <<= 1) {
            l_dp[r] += __shfl_xor(l_dp[r], off, 64);
            l_dd[r] += __shfl_xor(l_dd[r], off, 64);
        }
    }
#pragma unroll
    for (int r = 0; r < 4; r++) {
        int qrow = q0 + quad * 4 + r;
        bool rm = (bias_s[(size_t)n * GS + qrow] == 0.0f);
        float idp = 1.f / l_dp[r], idd = 1.f / l_dd[r];
        float v0 = rm ? 0.5f * (odp0[r] * idp + odd0[r] * idd) : 0.f;
        float v1 = rm ? 0.5f * (odp1[r] * idp + odd1[r] * idd) : 0.f;
        float* ob = out + ((size_t)n * GS + qrow) * 256 + h * 32;
        ob[m16] = v0;
        ob[16 + m16] = v1;
    }
}

// ---------------------------------------------------------------------------
extern "C" void kernel_launch(void* const* d_in, const int* in_sizes, int n_in,
                              void* d_out, int out_size, void* d_ws,
                              size_t ws_size, hipStream_t stream) {
    const float* protein   = (const float*)d_in[0];
    const float* smx       = (const float*)d_in[1];
    const int*   mask_prot = (const int*)d_in[2];
    const int*   mask_sm   = (const int*)d_in[3];
    const float* Wk_p = (const float*)d_in[4];
    const float* Wv_p = (const float*)d_in[5];
    const float* Wq_d = (const float*)d_in[6];
    const float* Wk_d = (const float*)d_in[7];
    const float* Wv_d = (const float*)d_in[8];
    float* out = (float*)d_out;

    char* ws = (char*)d_ws;
    unsigned short* prot_g = (unsigned short*)ws; ws += (size_t)N_B * GP * 256 * 2;
    unsigned short* sm_g   = (unsigned short*)ws; ws += (size_t)N_B * GS * 256 * 2;
    unsigned short* WTbig  = (unsigned short*)ws; ws += (size_t)512 * 256 * 2;
    unsigned short* WTsml  = (unsigned short*)ws; ws += (size_t)768 * 256 * 2;
    unsigned short* Kp     = (unsigned short*)ws; ws += (size_t)N_B * H_N * GP * 32 * 2;
    unsigned short* Vp     = (unsigned short*)ws; ws += (size_t)N_B * H_N * GP * 32 * 2;
    unsigned short* Vpt    = (unsigned short*)ws; ws += (size_t)N_B * H_N * GP * 32 * 2;
    unsigned short* Qd     = (unsigned short*)ws; ws += (size_t)N_B * H_N * GS * 32 * 2;
    unsigned short* Ksd    = (unsigned short*)ws; ws += (size_t)N_B * H_N * GS * 32 * 2;
    unsigned short* Vsd    = (unsigned short*)ws; ws += (size_t)N_B * H_N * GS * 32 * 2;
    unsigned short* Vsdt   = (unsigned short*)ws; ws += (size_t)N_B * H_N * GS * 32 * 2;
    float* bias_p = (float*)ws; ws += (size_t)N_B * GP * 4;
    float* bias_s = (float*)ws; ws += (size_t)N_B * GS * 4;

    // 1. grouping (fp32 -> bf16) + mask biases (log2 domain)
    int totalP = N_B * GP * 64;
    group_mean_bf16<<<totalP / 256, 256, 0, stream>>>(
        (const float4*)protein, (ushort4*)prot_g, totalP);
    int totalS = N_B * GS * 64;
    group_mean_bf16<<<totalS / 256, 256, 0, stream>>>(
        (const float4*)smx, (ushort4*)sm_g, totalS);
    group_mask_bias<<<(N_B * GP) / 256, 256, 0, stream>>>(
        mask_prot, bias_p, N_B * GP);
    group_mask_bias<<<(N_B * GS) / 256, 256, 0, stream>>>(
        mask_sm, bias_s, N_B * GS);

    // 2. weight transpose+concat (coalesced, LDS-tiled)
    wtrans_bf16<<<dim3(16, 2), 256, 0, stream>>>(Wk_p, Wv_p, Wv_p, WTbig);
    wtrans_bf16<<<dim3(16, 3), 256, 0, stream>>>(Wq_d, Wk_d, Wv_d, WTsml);

    // 3. MFMA projections -> head-major bf16 (Q pre-scaled by log2e)
    gemm_bf16<<<dim3(4, (N_B * GP) / 128), 256, 0, stream>>>(
        prot_g, WTbig, Kp, Vp, Vp, GP, 10, 1.0f);
    gemm_bf16<<<dim3(6, (N_B * GS) / 128), 256, 0, stream>>>(
        sm_g, WTsml, Qd, Ksd, Vsd, GS, 8, LOG2E);

    // 4. V -> V^T (A-frag layout, chunk-permuted columns)
    vtrans<<<dim3(GP / 128, N_B * H_N), 256, 0, stream>>>(Vp, Vpt, GP);
    vtrans<<<dim3(GS / 128, N_B * H_N), 256, 0, stream>>>(Vsd, Vsdt, GS);

    // 5. barrier-free dual-stream flash-MFMA attention + merge
    attn_mfma<<<N_B * H_N * 4, 256, 0, stream>>>(Qd, Kp, Vpt, Ksd, Vsdt,
                                                 bias_p, bias_s, out);
}

// Round 5
// 293.823 us; speedup vs baseline: 3.5359x; 1.1229x over previous
//
#include <hip/hip_runtime.h>
#include <cstdint>
#include <cstddef>

// Problem constants (fixed by setup_inputs)
#define N_B 32
#define D_MODEL 256
#define H_N 8
#define HD 32
#define GP 1024   // grouped protein length
#define GS 256    // grouped sm length
#define LOG2E 1.4426950408889634f

typedef __attribute__((ext_vector_type(8))) short short8;   // 8 bf16 = 4 VGPRs
typedef __attribute__((ext_vector_type(4))) float floatx4;

#if __has_builtin(__builtin_amdgcn_exp2f)
#define EXP2(x) __builtin_amdgcn_exp2f(x)
#else
#define EXP2(x) exp2f(x)
#endif

__device__ __forceinline__ unsigned short f2bf(float f) {
    unsigned u = __float_as_uint(f);
    u = (u + 0x7FFFu + ((u >> 16) & 1u)) >> 16;   // RNE
    return (unsigned short)u;
}

// pack two floats -> bf16x2 (lo = a, hi = b)
__device__ __forceinline__ unsigned pack_bf16(float a, float b) {
    unsigned ua = __float_as_uint(a) + 0x8000u;
    unsigned ub = __float_as_uint(b) + 0x8000u;
    return __builtin_amdgcn_perm(ub, ua, 0x07060302);  // [b.hi16][a.hi16]
}

// ---------------------------------------------------------------------------
// Fused prologue: both group-means (fp32 -> bf16) + both mask biases.
// Flat gid ranges: [0,A) P-mean, [A,A+B) S-mean, then P-mask, S-mask.
#define PRO_A (N_B * GP * 64)
#define PRO_B (N_B * GS * 64)
#define PRO_C (N_B * GP)
#define PRO_D (N_B * GS)
__global__ __launch_bounds__(256) void prologue(
        const float4* __restrict__ prot, const float4* __restrict__ smx,
        const int* __restrict__ mp, const int* __restrict__ ms,
        ushort4* __restrict__ prot_g, ushort4* __restrict__ sm_g,
        float* __restrict__ bias_p, float* __restrict__ bias_s) {
    int gid = blockIdx.x * 256 + threadIdx.x;
    if (gid < PRO_A + PRO_B) {
        const float4* x; ushort4* xg; int g2;
        if (gid < PRO_A) { x = prot; xg = prot_g; g2 = gid; }
        else { x = smx; xg = sm_g; g2 = gid - PRO_A; }
        int row = g2 >> 6, c = g2 & 63;
        const float4* p = x + (size_t)row * 256 + c;
        float4 a = p[0], b = p[64], cc = p[128], d = p[192];
        ushort4 r;
        r.x = f2bf(0.25f * (a.x + b.x + cc.x + d.x));
        r.y = f2bf(0.25f * (a.y + b.y + cc.y + d.y));
        r.z = f2bf(0.25f * (a.z + b.z + cc.z + d.z));
        r.w = f2bf(0.25f * (a.w + b.w + cc.w + d.w));
        xg[g2] = r;
    } else {
        int g2 = gid - (PRO_A + PRO_B);
        const int* m; float* bias;
        if (g2 < PRO_C) { m = mp; bias = bias_p; }
        else { m = ms; bias = bias_s; g2 -= PRO_C; }
        const int* p = m + (size_t)g2 * 4;
        bias[g2] = (p[0] | p[1] | p[2] | p[3]) ? 0.0f : -1442695.0f;
    }
}

// ---------------------------------------------------------------------------
// W [K=256][N=256] fp32 -> concatenated transposed bf16 WT[p*256+col][k].
// 64x64 tiles via LDS; grid.y in [0,5) selects which of the 5 weights.
__global__ __launch_bounds__(256) void wtrans_bf16(
        const float* __restrict__ Wk_p, const float* __restrict__ Wv_p,
        const float* __restrict__ Wq_d, const float* __restrict__ Wk_d,
        const float* __restrict__ Wv_d,
        unsigned short* __restrict__ WTbig, unsigned short* __restrict__ WTsml) {
    __shared__ unsigned short sT[64 * 65];
    int y = blockIdx.y;
    const float* W; unsigned short* WT; int pidx;
    if (y < 2) { W = (y == 0) ? Wk_p : Wv_p; WT = WTbig; pidx = y; }
    else {
        int q = y - 2;
        W = (q == 0) ? Wq_d : (q == 1 ? Wk_d : Wv_d);
        WT = WTsml; pidx = q;
    }
    int kt = blockIdx.x >> 2, ct = blockIdx.x & 3;
    int k0 = kt * 64, c0 = ct * 64;
    int t = threadIdx.x;
#pragma unroll
    for (int j = 0; j < 4; j++) {
        int idx = j * 256 + t;
        int kr = idx >> 4, cf = idx & 15;
        float4 v = *(const float4*)&W[(size_t)(k0 + kr) * 256 + c0 + cf * 4];
        sT[(cf * 4 + 0) * 65 + kr] = f2bf(v.x);
        sT[(cf * 4 + 1) * 65 + kr] = f2bf(v.y);
        sT[(cf * 4 + 2) * 65 + kr] = f2bf(v.z);
        sT[(cf * 4 + 3) * 65 + kr] = f2bf(v.w);
    }
    __syncthreads();
#pragma unroll
    for (int j = 0; j < 8; j++) {
        int idx = j * 256 + t;
        int cw = idx >> 5, kq = idx & 31;
        unsigned lo = sT[cw * 65 + kq * 2];
        unsigned hi = sT[cw * 65 + kq * 2 + 1];
        ((unsigned*)WT)[((size_t)pidx * 256 + c0 + cw) * 128 + (k0 >> 1) + kq] =
            lo | (hi << 16);
    }
}

// ---------------------------------------------------------------------------
// Transpose head-major V [nh][Gk][32] -> Vt [nh][32][Gk], with per-32-key
// column permutation pos = 2*(k&15) + (k>>4). grid: y = nh, x in [0,10):
// x<8 -> P slab x; else S slab x-8.
__global__ __launch_bounds__(256) void vtrans(
        const unsigned short* __restrict__ Vp, unsigned short* __restrict__ Vpt,
        const unsigned short* __restrict__ Vs, unsigned short* __restrict__ Vst) {
    __shared__ unsigned short sT[32 * 132];
    int nh = blockIdx.y, bx = blockIdx.x;
    const unsigned short* V; unsigned short* Vt; int Gk, kbase;
    if (bx < 8) { V = Vp; Vt = Vpt; Gk = GP; kbase = bx << 7; }
    else { V = Vs; Vt = Vst; Gk = GS; kbase = (bx - 8) << 7; }
    const uint4* src = (const uint4*)(V + ((size_t)nh * Gk + kbase) * 32);
    int t = threadIdx.x;
#pragma unroll
    for (int j = 0; j < 2; j++) {
        int idx = j * 256 + t;
        int kk = idx >> 2, dq = idx & 3;
        union { uint4 u; unsigned short s[8]; } w;
        w.u = src[kk * 4 + dq];
#pragma unroll
        for (int e = 0; e < 8; e++)
            sT[(dq * 8 + e) * 132 + kk] = w.s[e];
    }
    __syncthreads();
#pragma unroll
    for (int j = 0; j < 2; j++) {
        int idx = j * 256 + t;
        int d = idx >> 4, pu = idx & 15;
        union { uint4 u; unsigned short s[8]; } w;
#pragma unroll
        for (int e = 0; e < 8; e++) {
            int p = pu * 8 + e;
            int chunk = p >> 5, p32 = p & 31;
            int k32 = (p32 >> 1) + ((p32 & 1) << 4);
            w.s[e] = sT[d * 132 + chunk * 32 + k32];
        }
        *(uint4*)(Vt + ((size_t)nh * 32 + d) * Gk + kbase + pu * 8) = w.u;
    }
}

// ---------------------------------------------------------------------------
// Unified bf16 MFMA GEMM (both parts in one launch): blockIdx.x < 1024 ->
// big part (A=prot_g, 512 cols), else small part (A=sm_g, 768 cols).
// global_load_lds(16B) staging into seg-rotated unpadded LDS (conflict-free
// b128 frag reads + lane-linear async-copy dest).
__global__ __launch_bounds__(256) void gemm_bf16(
        const unsigned short* __restrict__ Abig,
        const unsigned short* __restrict__ WTbig,
        const unsigned short* __restrict__ Asml,
        const unsigned short* __restrict__ WTsml,
        unsigned short* __restrict__ Kp, unsigned short* __restrict__ Vp,
        unsigned short* __restrict__ Qd, unsigned short* __restrict__ Ksd,
        unsigned short* __restrict__ Vsd) {
    __shared__ alignas(16) unsigned short As[128 * 64];
    __shared__ alignas(16) unsigned short Bs[128 * 64];
    int id = blockIdx.x;
    const unsigned short *A, *WT;
    unsigned short *o0, *o1, *o2;
    int Gg, lgG, row0, col0;
    float scale0;
    if (id < 1024) {
        A = Abig; WT = WTbig; o0 = Kp; o1 = Vp; o2 = Vp;
        Gg = GP; lgG = 10; scale0 = 1.0f;
        col0 = (id & 3) << 7; row0 = (id >> 2) << 7;
    } else {
        int t = id - 1024;
        A = Asml; WT = WTsml; o0 = Qd; o1 = Ksd; o2 = Vsd;
        Gg = GS; lgG = 8; scale0 = LOG2E;
        col0 = (t % 6) << 7; row0 = (t / 6) << 7;
    }
    const int tid = threadIdx.x;
    const int ln = tid & 63, wave = tid >> 6;
    const int m16 = ln & 15, quad = ln >> 4;
    const int wm = (wave & 1) * 64, wn = (wave >> 1) * 64;

    // staging lane constants: slab j covers units (j*4+wave)*64 + ln
    const uint4* gA[4];
    const uint4* gB[4];
    unsigned ldsoff[4];
#pragma unroll
    for (int j = 0; j < 4; j++) {
        int u = (j * 4 + wave) * 64 + ln;
        int r = u >> 3, s = u & 7;
        int sg = (s - r) & 7;
        gA[j] = (const uint4*)A + (size_t)(row0 + r) * 32 + sg;
        gB[j] = (const uint4*)WT + (size_t)(col0 + r) * 32 + sg;
        ldsoff[j] = (unsigned)((j * 4 + wave) * 512);   // shorts
    }
    // frag read byte-addresses (k0-invariant; kh toggles bit 6)
    int aaddr[4], baddr[4];
#pragma unroll
    for (int i = 0; i < 4; i++) {
        int rA = wm + i * 16 + m16;
        aaddr[i] = rA * 128 + ((quad + rA) & 7) * 16;
        int rB = wn + i * 16 + m16;
        baddr[i] = rB * 128 + ((quad + rB) & 7) * 16;
    }

    floatx4 acc[4][4] = {};
    for (int ko = 0; ko < 32; ko += 8) {     // k in uint4 units (256/8)
        __syncthreads();
#pragma unroll
        for (int j = 0; j < 4; j++) {
            __builtin_amdgcn_global_load_lds(
                (const __attribute__((address_space(1))) void*)(gA[j] + ko),
                (__attribute__((address_space(3))) void*)&As[ldsoff[j]], 16, 0, 0);
            __builtin_amdgcn_global_load_lds(
                (const __attribute__((address_space(1))) void*)(gB[j] + ko),
                (__attribute__((address_space(3))) void*)&Bs[ldsoff[j]], 16, 0, 0);
        }
        __syncthreads();
#pragma unroll
        for (int kh = 0; kh < 2; kh++) {
            short8 af[4], bfr[4];
#pragma unroll
            for (int i = 0; i < 4; i++) {
                af[i]  = *(const short8*)((const char*)As + (aaddr[i] ^ (kh << 6)));
                bfr[i] = *(const short8*)((const char*)Bs + (baddr[i] ^ (kh << 6)));
            }
#pragma unroll
            for (int im = 0; im < 4; im++)
#pragma unroll
                for (int in = 0; in < 4; in++)
                    acc[im][in] = __builtin_amdgcn_mfma_f32_16x16x32_bf16(
                        af[im], bfr[in], acc[im][in], 0, 0, 0);
        }
    }
    // epilogue: C layout col=lane&15, row=quad*4+reg; head-major bf16 out
#pragma unroll
    for (int im = 0; im < 4; im++) {
#pragma unroll
        for (int in = 0; in < 4; in++) {
            int colg = col0 + wn + in * 16 + m16;
            int p = colg >> 8, h = (colg >> 5) & 7, d = colg & 31;
            unsigned short* ob = (p == 0) ? o0 : (p == 1 ? o1 : o2);
            float sc = (p == 0) ? scale0 : 1.0f;
#pragma unroll
            for (int r = 0; r < 4; r++) {
                int Mrow = row0 + wm + im * 16 + quad * 4 + r;
                int nb = Mrow >> lgG, g = Mrow & (Gg - 1);
                ob[(((size_t)nb * 8 + h) * Gg + g) * 32 + d] = f2bf(acc[im][in][r] * sc);
            }
        }
    }
}

// ---------------------------------------------------------------------------
// Barrier-free flash attention, 32 queries/wave (two 16-q tiles sharing K/V
// frags) + register double-buffered prefetch of next chunk's frags+biases.
struct KVFrag { uint4 k0, k1, v0, v1; float b0, b1; };

__device__ __forceinline__ KVFrag load_frag(
        const uint4* K4, const uint4* V4, const float* bias,
        int c, int Gk8, int m16, int quad) {
    KVFrag f;
    f.k0 = K4[(c * 32 + m16) * 4 + quad];
    f.k1 = K4[(c * 32 + 16 + m16) * 4 + quad];
    f.v0 = V4[(size_t)m16 * Gk8 + c * 4 + quad];
    f.v1 = V4[(size_t)(16 + m16) * Gk8 + c * 4 + quad];
    f.b0 = bias[c * 32 + m16];
    f.b1 = bias[c * 32 + 16 + m16];
    return f;
}

__device__ __forceinline__ void attn_stream(
        const unsigned short* __restrict__ Kb,
        const unsigned short* __restrict__ Vtb,
        const float* __restrict__ bias, int Lk,
        short8 qfA, short8 qfB, unsigned* sPw,
        int m16, int quad, float* lA, float* lB,
        floatx4& oA0, floatx4& oA1, floatx4& oB0, floatx4& oB1) {
    const uint4* K4 = (const uint4*)Kb;
    const uint4* V4 = (const uint4*)Vtb;
    const int Gk8 = Lk >> 3;
    const int nchunks = Lk >> 5;
    KVFrag cur = load_frag(K4, V4, bias, 0, Gk8, m16, quad);
    for (int c = 0; c < nchunks; c++) {
        int cn = (c + 1 < nchunks) ? c + 1 : c;
        KVFrag nxt = load_frag(K4, V4, bias, cn, Gk8, m16, quad);
        union { uint4 u; short8 v; } t0, t1, pA, pB;
        t0.u = cur.k0; t1.u = cur.k1;
        floatx4 z = {0.f, 0.f, 0.f, 0.f};
        floatx4 sA0 = __builtin_amdgcn_mfma_f32_16x16x32_bf16(qfA, t0.v, z, 0, 0, 0);
        floatx4 sA1 = __builtin_amdgcn_mfma_f32_16x16x32_bf16(qfA, t1.v, z, 0, 0, 0);
        floatx4 sB0 = __builtin_amdgcn_mfma_f32_16x16x32_bf16(qfB, t0.v, z, 0, 0, 0);
        floatx4 sB1 = __builtin_amdgcn_mfma_f32_16x16x32_bf16(qfB, t1.v, z, 0, 0, 0);
#pragma unroll
        for (int r = 0; r < 4; r++) {            // row q = quad*4 + r
            float eA0 = EXP2(sA0[r] + cur.b0);
            float eA1 = EXP2(sA1[r] + cur.b1);
            float eB0 = EXP2(sB0[r] + cur.b0);
            float eB1 = EXP2(sB1[r] + cur.b1);
            lA[r] += eA0 + eA1;
            lB[r] += eB0 + eB1;
            sPw[(quad * 4 + r) * 20 + m16] = pack_bf16(eA0, eA1);
            sPw[320 + (quad * 4 + r) * 20 + m16] = pack_bf16(eB0, eB1);
        }
        pA.u = *(const uint4*)&sPw[m16 * 20 + quad * 4];
        pB.u = *(const uint4*)&sPw[320 + m16 * 20 + quad * 4];
        t0.u = cur.v0; t1.u = cur.v1;
        oA0 = __builtin_amdgcn_mfma_f32_16x16x32_bf16(pA.v, t0.v, oA0, 0, 0, 0);
        oA1 = __builtin_amdgcn_mfma_f32_16x16x32_bf16(pA.v, t1.v, oA1, 0, 0, 0);
        oB0 = __builtin_amdgcn_mfma_f32_16x16x32_bf16(pB.v, t0.v, oB0, 0, 0, 0);
        oB1 = __builtin_amdgcn_mfma_f32_16x16x32_bf16(pB.v, t1.v, oB1, 0, 0, 0);
        cur = nxt;
    }
}

__global__ __launch_bounds__(256) void attn_mfma(
        const unsigned short* __restrict__ Qd, const unsigned short* __restrict__ Kp,
        const unsigned short* __restrict__ Vpt, const unsigned short* __restrict__ Ksd,
        const unsigned short* __restrict__ Vsdt, const float* __restrict__ bias_p,
        const float* __restrict__ bias_s, float* __restrict__ out) {
    __shared__ alignas(16) unsigned sP[4][640];
    const int b = blockIdx.x;
    const int n = b >> 4, h = (b >> 1) & 7, qq = b & 1;
    const int tid = threadIdx.x, wave = tid >> 6, ln = tid & 63;
    const int m16 = ln & 15, quad = ln >> 4;
    const int q0 = qq * 128 + wave * 32;     // tile A: q0.., tile B: q0+16..
    unsigned* sPw = sP[wave];

    union { uint4 u; short8 v; } qfA, qfB;
    qfA.u = ((const uint4*)Qd)[(((size_t)n * 8 + h) * GS + q0 + m16) * 4 + quad];
    qfB.u = ((const uint4*)Qd)[(((size_t)n * 8 + h) * GS + q0 + 16 + m16) * 4 + quad];

    float lAdp[4] = {0, 0, 0, 0}, lBdp[4] = {0, 0, 0, 0};
    float lAdd[4] = {0, 0, 0, 0}, lBdd[4] = {0, 0, 0, 0};
    floatx4 oAdp0 = {}, oAdp1 = {}, oBdp0 = {}, oBdp1 = {};
    floatx4 oAdd0 = {}, oAdd1 = {}, oBdd0 = {}, oBdd1 = {};

    attn_stream(Kp + ((size_t)n * 8 + h) * GP * 32,
                Vpt + ((size_t)n * 8 + h) * GP * 32,
                bias_p + (size_t)n * GP, GP, qfA.v, qfB.v, sPw, m16, quad,
                lAdp, lBdp, oAdp0, oAdp1, oBdp0, oBdp1);
    attn_stream(Ksd + ((size_t)n * 8 + h) * GS * 32,
                Vsdt + ((size_t)n * 8 + h) * GS * 32,
                bias_s + (size_t)n * GS, GS, qfA.v, qfB.v, sPw, m16, quad,
                lAdd, lBdd, oAdd0, oAdd1, oBdd0, oBdd1);

#pragma unroll
    for (int r = 0; r < 4; r++) {
#pragma unroll
        for (int off = 1; off < 16; off <<= 1) {
            lAdp[r] += __shfl_xor(lAdp[r], off, 64);
            lBdp[r] += __shfl_xor(lBdp[r], off, 64);
            lAdd[r] += __shfl_xor(lAdd[r], off, 64);
            lBdd[r] += __shfl_xor(lBdd[r], off, 64);
        }
    }
#pragma unroll
    for (int r = 0; r < 4; r++) {
        // tile A
        int qrowA = q0 + quad * 4 + r;
        bool rmA = (bias_s[(size_t)n * GS + qrowA] == 0.0f);
        float idpA = 1.f / lAdp[r], iddA = 1.f / lAdd[r];
        float* obA = out + ((size_t)n * GS + qrowA) * 256 + h * 32;
        obA[m16]      = rmA ? 0.5f * (oAdp0[r] * idpA + oAdd0[r] * iddA) : 0.f;
        obA[16 + m16] = rmA ? 0.5f * (oAdp1[r] * idpA + oAdd1[r] * iddA) : 0.f;
        // tile B
        int qrowB = q0 + 16 + quad * 4 + r;
        bool rmB = (bias_s[(size_t)n * GS + qrowB] == 0.0f);
        float idpB = 1.f / lBdp[r], iddB = 1.f / lBdd[r];
        float* obB = out + ((size_t)n * GS + qrowB) * 256 + h * 32;
        obB[m16]      = rmB ? 0.5f * (oBdp0[r] * idpB + oBdd0[r] * iddB) : 0.f;
        obB[16 + m16] = rmB ? 0.5f * (oBdp1[r] * idpB + oBdd1[r] * iddB) : 0.f;
    }
}

// ---------------------------------------------------------------------------
extern "C" void kernel_launch(void* const* d_in, const int* in_sizes, int n_in,
                              void* d_out, int out_size, void* d_ws,
                              size_t ws_size, hipStream_t stream) {
    const float* protein   = (const float*)d_in[0];
    const float* smx       = (const float*)d_in[1];
    const int*   mask_prot = (const int*)d_in[2];
    const int*   mask_sm   = (const int*)d_in[3];
    const float* Wk_p = (const float*)d_in[4];
    const float* Wv_p = (const float*)d_in[5];
    const float* Wq_d = (const float*)d_in[6];
    const float* Wk_d = (const float*)d_in[7];
    const float* Wv_d = (const float*)d_in[8];
    float* out = (float*)d_out;

    char* ws = (char*)d_ws;
    unsigned short* prot_g = (unsigned short*)ws; ws += (size_t)N_B * GP * 256 * 2;
    unsigned short* sm_g   = (unsigned short*)ws; ws += (size_t)N_B * GS * 256 * 2;
    unsigned short* WTbig  = (unsigned short*)ws; ws += (size_t)512 * 256 * 2;
    unsigned short* WTsml  = (unsigned short*)ws; ws += (size_t)768 * 256 * 2;
    unsigned short* Kp     = (unsigned short*)ws; ws += (size_t)N_B * H_N * GP * 32 * 2;
    unsigned short* Vp     = (unsigned short*)ws; ws += (size_t)N_B * H_N * GP * 32 * 2;
    unsigned short* Vpt    = (unsigned short*)ws; ws += (size_t)N_B * H_N * GP * 32 * 2;
    unsigned short* Qd     = (unsigned short*)ws; ws += (size_t)N_B * H_N * GS * 32 * 2;
    unsigned short* Ksd    = (unsigned short*)ws; ws += (size_t)N_B * H_N * GS * 32 * 2;
    unsigned short* Vsd    = (unsigned short*)ws; ws += (size_t)N_B * H_N * GS * 32 * 2;
    unsigned short* Vsdt   = (unsigned short*)ws; ws += (size_t)N_B * H_N * GS * 32 * 2;
    float* bias_p = (float*)ws; ws += (size_t)N_B * GP * 4;
    float* bias_s = (float*)ws; ws += (size_t)N_B * GS * 4;

    // 1. fused prologue: group means (bf16) + mask biases (log2 domain)
    prologue<<<(PRO_A + PRO_B + PRO_C + PRO_D) / 256, 256, 0, stream>>>(
        (const float4*)protein, (const float4*)smx, mask_prot, mask_sm,
        (ushort4*)prot_g, (ushort4*)sm_g, bias_p, bias_s);

    // 2. weight transpose+concat (all 5 weights, one launch)
    wtrans_bf16<<<dim3(16, 5), 256, 0, stream>>>(
        Wk_p, Wv_p, Wq_d, Wk_d, Wv_d, WTbig, WTsml);

    // 3. unified MFMA projections -> head-major bf16 (Q pre-scaled by log2e)
    gemm_bf16<<<1024 + 384, 256, 0, stream>>>(
        prot_g, WTbig, sm_g, WTsml, Kp, Vp, Qd, Ksd, Vsd);

    // 4. V -> V^T (A-frag layout, chunk-permuted columns), both in one launch
    vtrans<<<dim3(10, N_B * H_N), 256, 0, stream>>>(Vp, Vpt, Vsd, Vsdt);

    // 5. barrier-free dual-stream flash-MFMA attention + merge
    attn_mfma<<<N_B * H_N * 2, 256, 0, stream>>>(Qd, Kp, Vpt, Ksd, Vsdt,
                                                 bias_p, bias_s, out);
}